// Round 10
// baseline (547.000 us; speedup 1.0000x reference)
//
#include <hip/hip_runtime.h>
#include <cstdint>
#include <cstddef>

// ---------------------------------------------------------------------------
// AlphaNet: features -> BN -> conv(1x3,16) -> relu -> fc1(43200->512) -> relu
//          -> fc2(512->128) -> sigmoid -> fc3(128->1)
// R19: stage_a reverted to R15 (LDS-staged b128 stores; R18's f16x2 direct
//   stores regressed). gemm_fc1 rebuilt as a DEEP pipeline (T4): BK=32,
//   4-stage LDS ring (128 KB), prefetch depth 3, vmcnt(8) steady-state (2
//   stages always in flight, never drains to 0), 1 barrier/step. In-flight
//   bytes/CU rise 3-6x to attack the measured 5.5-5.8 TB/s delivery pin
//   (latency x in-flight limited hypothesis; m97-class delivers ~13 TB/s).
//   Read slot = (quad + (m16>>1))&3 (constant/lane, conflict-free).
//   A row-major + pre-swizzled gload source; W retiled [nt][1350][256][32].
// ---------------------------------------------------------------------------

typedef _Float16 f16;
typedef f16 f16x2 __attribute__((ext_vector_type(2)));
typedef f16 f16x8 __attribute__((ext_vector_type(8)));
typedef float f32x4 __attribute__((ext_vector_type(4)));

#define CHUNK   2048               // samples per pipeline pass (2 passes)
#define K_FC1   43200              // 16*270*10
#define KT32    1350               // K-tiles of 32
#define TB32    8192               // f16 per W (nt,kt) tile: 256 rows x 32 k
#define STG_F   16384              // f16 per ring stage (A 8192 + B 8192)

__device__ __forceinline__ float fillv(float x) { return isfinite(x) ? x : 0.0f; }

// ---------------------------------------------------------------------------
// Kernel 1: fc1_w fp32 -> f16, retiled to [nt(2)][kt(1350)][256][32] with
// 16B-unit swizzle: chunk c of row r stored at slot (c + (r>>1)) & 3.
// One block per (nt,kt) = 2700 blocks; 1024 units each.
// ---------------------------------------------------------------------------
__global__ __launch_bounds__(256) void retile_w(const float* __restrict__ w,
                                                f16* __restrict__ Wt) {
    const int bid = blockIdx.x;               // nt*1350 + kt
    const int nt = bid / KT32, kt = bid % KT32;
    const int t = threadIdx.x;
    f16* dst = Wt + (size_t)bid * TB32;
    #pragma unroll
    for (int j = 0; j < 4; ++j) {
        int q = t + 256 * j;                  // 0..1023 16B units
        int r = q >> 2, c = q & 3;
        const float* s = w + (size_t)(nt * 256 + r) * K_FC1 + kt * 32 + c * 8;
        float4 x = *(const float4*)s;
        float4 y = *(const float4*)(s + 4);
        f16x8 o = { (f16)x.x, (f16)x.y, (f16)x.z, (f16)x.w,
                    (f16)y.x, (f16)y.y, (f16)y.z, (f16)y.w };
        int p = (c + (r >> 1)) & 3;
        *(f16x8*)(dst + r * 32 + (p << 3)) = o;
    }
}

// ---------------------------------------------------------------------------
// Kernel 2 (R15-proven): per-sample features + folded-BN conv + relu -> A16
// (scaled 2^-8), plain row-major [sample][43200] f16; conv outputs staged in
// LDS then written as contiguous b128 streams.
// ---------------------------------------------------------------------------
__global__ __launch_bounds__(256) void stage_a(
    const float* __restrict__ data, const float* __restrict__ bn_g,
    const float* __restrict__ bn_b, const float* __restrict__ bn_m,
    const float* __restrict__ bn_v, const float* __restrict__ conv_w,
    const float* __restrict__ conv_b, f16* __restrict__ A16, int n0)
{
    __shared__ __align__(16) float pool[5400];
    __shared__ __align__(16) float feat[270 * 12];
    __shared__ float cwf[48];
    __shared__ float cbf[16];
    __shared__ int   pi[105], pj[105];

    float* raw = pool;
    f16*   cstage = (f16*)pool;

    const int t = threadIdx.x;
    const int n = n0 + blockIdx.x;
    const float4* src4 = (const float4*)(data + (size_t)n * 1800);
    for (int i = t; i < 450; i += 256) ((float4*)pool)[i] = src4[i];

    {
        float a  = bn_g[0] * rsqrtf(bn_v[0] + 1e-5f);
        float bb = bn_b[0] - bn_m[0] * a;
        if (t < 48) cwf[t] = conv_w[t] * a;
        if (t < 16) cbf[t] = conv_b[t] + bb * (conv_w[3 * t] + conv_w[3 * t + 1] + conv_w[3 * t + 2]);
    }
    if (t < 105) {
        int i = 0, rem = t;
        while (rem >= 14 - i) { rem -= 14 - i; ++i; }
        pi[t] = i; pj[t] = i + 1 + rem;
    }
    __syncthreads();

    if (t < 180) {
        int f = t / 12, w = t % 12;
        int base = f * 120 + w * 10;
        const float2* r2 = (const float2*)(raw + base);
        float2 p0 = r2[0], p1 = r2[1], p2 = r2[2], p3 = r2[3], p4 = r2[4];
        float x[10] = { p0.x, p0.y, p1.x, p1.y, p2.x, p2.y, p3.x, p3.y, p4.x, p4.y };
        float sum = 0.f;
        #pragma unroll
        for (int s = 0; s < 10; ++s) sum += x[s];
        float mean = sum * 0.1f;
        float ret = x[9] / x[0] - 1.0f;
        float dl = 0.f;
        #pragma unroll
        for (int s = 0; s < 10; ++s) dl += x[s] * ((float)(s + 1) * (1.0f / 55.0f));
        float var = 0.f;
        float d[10];
        #pragma unroll
        for (int s = 0; s < 10; ++s) { d[s] = x[s] - mean; var += d[s] * d[s]; }
        float2* w2p = (float2*)(raw + base);
        #pragma unroll
        for (int s = 0; s < 5; ++s) w2p[s] = make_float2(d[2 * s], d[2 * s + 1]);
        var *= (1.0f / 9.0f);
        float sd = sqrtf(var);
        feat[(210 + f) * 12 + w] = fillv(sd);
        feat[(225 + f) * 12 + w] = fillv(mean / sd);
        feat[(240 + f) * 12 + w] = fillv(ret);
        feat[(255 + f) * 12 + w] = fillv(dl);
    }
    __syncthreads();

    for (int q = t; q < 1260; q += 256) {
        int p = q / 12, w = q % 12;
        int i = pi[p], j = pj[p];
        const float2* ri = (const float2*)(raw + i * 120 + w * 10);
        const float2* rj = (const float2*)(raw + j * 120 + w * 10);
        float cv = 0.f;
        #pragma unroll
        for (int s = 0; s < 5; ++s) {
            float2 ai = ri[s], aj = rj[s];
            cv += ai.x * aj.x + ai.y * aj.y;
        }
        cv *= (1.0f / 9.0f);
        float si = feat[(210 + i) * 12 + w], sj = feat[(210 + j) * 12 + w];
        feat[p * 12 + w]         = fillv(cv / (si * sj) * 0.9f);
        feat[(105 + p) * 12 + w] = fillv(cv);
    }
    __syncthreads();   // raw dead; pool becomes cstage

    f16* abase = A16 + (size_t)blockIdx.x * K_FC1;
    for (int p = 0; p < 4; ++p) {
        #pragma unroll
        for (int j = 0; j < 5; ++j) {
            int item = t + (j << 8);
            if (item < 1080) {
                int h = item >> 2, ocl = item & 3, oc = (p << 2) + ocl;
                const float4* f4 = (const float4*)(feat + h * 12);
                float4 fa = f4[0], fb = f4[1], fc = f4[2];
                float fv[12] = { fa.x, fa.y, fa.z, fa.w,
                                 fb.x, fb.y, fb.z, fb.w,
                                 fc.x, fc.y, fc.z, fc.w };
                float w0 = cwf[oc * 3], w1 = cwf[oc * 3 + 1], w2 = cwf[oc * 3 + 2];
                float bz = cbf[oc];
                int kl = ocl * 2700 + h * 10;
                #pragma unroll
                for (int q = 0; q < 5; ++q) {
                    float y0 = fmaf(w2, fv[2 * q + 2], fmaf(w1, fv[2 * q + 1], fmaf(w0, fv[2 * q], bz)));
                    float y1 = fmaf(w2, fv[2 * q + 3], fmaf(w1, fv[2 * q + 2], fmaf(w0, fv[2 * q + 1], bz)));
                    y0 = fminf(fmaxf(y0, 0.f) * 0.00390625f, 65000.f);
                    y1 = fminf(fmaxf(y1, 0.f) * 0.00390625f, 65000.f);
                    *(f16x2*)(cstage + kl + 2 * q) = f16x2{ (f16)y0, (f16)y1 };
                }
            }
        }
        __syncthreads();
        #pragma unroll
        for (int j = 0; j < 6; ++j) {
            int u = t + (j << 8);
            if (u < 1350) {
                f16x8 ov = *(const f16x8*)(cstage + u * 8);
                *(f16x8*)(abase + (size_t)(p * 1350 + u) * 8) = ov;
            }
        }
        __syncthreads();
    }
}

// ---------------------------------------------------------------------------
// Kernel 3: fc1 GEMM  Ysum[CHUNK,512] (+)= A * W^T (f16 MFMA)
// 256x256 tile, BK=32, 8 waves, 4-stage LDS ring (128 KB), depth-3 prefetch,
// counted vmcnt(8) in steady state (2 stages always in flight), 1 barrier per
// K-step. Grid 256 = 8 mt x 2 nt x 16 sk; mt=bid>>5 -> XCD(=bid&7) groups the
// 8 mt-blocks sharing one W K-window (L2-resident W, R14-verified).
// A row-major; staging pre-swizzles the global source (both-sides rule).
// Read slot = (quad + (m16>>1)) & 3: constant per lane, conflict-free.
// ---------------------------------------------------------------------------
__global__ __launch_bounds__(512, 2) void gemm_fc1(const f16* __restrict__ A,
                                                   const f16* __restrict__ W,
                                                   float* __restrict__ Ysum)
{
    extern __shared__ f16 lds[];   // 4 stages x 16384 f16 (A 8192 | B 8192)

    const int bid = blockIdx.x;                   // 256 blocks
    const int mt = bid >> 5;                      // 0..7  M-tile
    const int slot = bid & 31;                    // (nt,sk) -> XCD = slot&7
    const int nt = slot & 1;
    const int sk = slot >> 1;                     // 0..15
    const int kt0 = sk * 84 + (sk < 6 ? sk : 6);  // uneven split: 6x85 + 10x84
    const int cnt = 84 + (sk < 6 ? 1 : 0);

    const int tid = threadIdx.x;
    const int wave = tid >> 6, lane = tid & 63;
    const int quad = lane >> 4, m16 = lane & 15;
    const int slotr = (quad + (m16 >> 1)) & 3;    // read slot (const per lane)
    const int wm = (wave & 1) << 6;               // 0 / 64
    const int wn = (wave >> 1) << 5;              // 0/32/64/96

    // staging lanes: unit u = tid (and tid+512): row = u>>2 (+128), pos = u&3.
    // LDS pos p holds logical chunk (p - (r>>1))&3  ->  source k-chunk.
    const int s_r = tid >> 2, s_p = tid & 3;
    const int s_src = (s_p - (s_r >> 1)) & 3;
    const f16* A_l = A + (size_t)(mt * 256 + s_r) * K_FC1 + (size_t)kt0 * 32
                       + (s_src << 3);
    const f16* B_l = W + ((size_t)nt * KT32 + kt0) * TB32 + tid * 8;

    f32x4 acc[8][4] = {};
    f16x8 a[8], b[4];

#define STAGE(ST, KI) do {                                                     \
    const f16* ga_ = A_l + (size_t)(KI) * 32;                                  \
    f16* la_ = lds + (ST) * STG_F + tid * 8;                                   \
    __builtin_amdgcn_global_load_lds(                                          \
        (const __attribute__((address_space(1))) void*)ga_,                    \
        (__attribute__((address_space(3))) void*)la_, 16, 0, 0);               \
    __builtin_amdgcn_global_load_lds(                                          \
        (const __attribute__((address_space(1))) void*)(ga_ + (size_t)128 * K_FC1), \
        (__attribute__((address_space(3))) void*)(la_ + 4096), 16, 0, 0);      \
    const f16* gb_ = B_l + (size_t)(KI) * TB32;                                \
    f16* lb_ = lds + (ST) * STG_F + 8192 + tid * 8;                            \
    __builtin_amdgcn_global_load_lds(                                          \
        (const __attribute__((address_space(1))) void*)gb_,                    \
        (__attribute__((address_space(3))) void*)lb_, 16, 0, 0);               \
    __builtin_amdgcn_global_load_lds(                                          \
        (const __attribute__((address_space(1))) void*)(gb_ + 4096),           \
        (__attribute__((address_space(3))) void*)(lb_ + 4096), 16, 0, 0);      \
} while (0)

#define RD(ST) do {                                                            \
    const f16* As_ = lds + (ST) * STG_F + (slotr << 3);                        \
    const f16* Bs_ = As_ + 8192;                                               \
    _Pragma("unroll") for (int i_ = 0; i_ < 8; ++i_)                           \
        a[i_] = *(const f16x8*)(As_                                            \
            + (((i_ >> 2) * 128 + wm + (i_ & 3) * 16 + m16) << 5));            \
    _Pragma("unroll") for (int j_ = 0; j_ < 4; ++j_)                           \
        b[j_] = *(const f16x8*)(Bs_                                            \
            + (((j_ >> 1) * 128 + wn + (j_ & 1) * 16 + m16) << 5));            \
} while (0)

#define MMA() do {                                                             \
    _Pragma("unroll") for (int i_ = 0; i_ < 8; ++i_)                           \
    _Pragma("unroll") for (int j_ = 0; j_ < 4; ++j_)                           \
        acc[i_][j_] = __builtin_amdgcn_mfma_f32_16x16x32_f16(                  \
            a[i_], b[j_], acc[i_][j_], 0, 0, 0);                               \
} while (0)

    // prologue: stages 0,1,2 in flight; wait stage 0 (8 = 2 stages flying)
    STAGE(0, 0);
    STAGE(1, 1);
    STAGE(2, 2);
    asm volatile("s_waitcnt vmcnt(8)" ::: "memory");
    __builtin_amdgcn_s_barrier();

    #pragma unroll 1
    for (int ti = 0; ti < cnt; ++ti) {
        const int cs = ti & 3;
        // slot (ti+3)&3 == (ti-1)&3: its readers finished at the ti-1 barrier
        if (ti + 3 < cnt) STAGE((ti + 3) & 3, ti + 3);
        RD(cs);
        __builtin_amdgcn_s_setprio(1);
        MMA();
        __builtin_amdgcn_s_setprio(0);
        // wait stage ti+1 landed; keep 2 newer stages flying (never drain)
        if (ti + 3 < cnt) {
            asm volatile("s_waitcnt vmcnt(8)" ::: "memory");
            __builtin_amdgcn_s_barrier();
        } else if (ti + 2 < cnt) {
            asm volatile("s_waitcnt vmcnt(4)" ::: "memory");
            __builtin_amdgcn_s_barrier();
        } else if (ti + 1 < cnt) {
            asm volatile("s_waitcnt vmcnt(0)" ::: "memory");
            __builtin_amdgcn_s_barrier();
        }
    }

#undef STAGE
#undef RD
#undef MMA

    // C/D layout: col = lane&15, row = quad*4 + reg. Atomic split-K reduce.
    float* Yb = Ysum + (size_t)(mt * 256) * 512 + nt * 256;
    #pragma unroll
    for (int i = 0; i < 8; ++i) {
        const int row0 = (i >> 2) * 128 + wm + (i & 3) * 16 + quad * 4;
        #pragma unroll
        for (int j = 0; j < 4; ++j) {
            const int col = (j >> 1) * 128 + wn + (j & 1) * 16 + m16;
            #pragma unroll
            for (int r = 0; r < 4; ++r)
                unsafeAtomicAdd(&Yb[(size_t)(row0 + r) * 512 + col], acc[i][j][r]);
        }
    }
}

// ---------------------------------------------------------------------------
// Kernel 4: head = (relu(sum*256+b1)) -> fc2 + sigmoid -> fc3
// 8 samples/block, 128 threads -> 256 blocks per chunk.
// ---------------------------------------------------------------------------
__global__ __launch_bounds__(128) void head_fc23(const float* __restrict__ y1s,
                                                 const float* __restrict__ b1,
                                                 const float* __restrict__ w2,
                                                 const float* __restrict__ b2,
                                                 const float* __restrict__ w3,
                                                 const float* __restrict__ b3,
                                                 float* __restrict__ out, int n0)
{
    __shared__ float Ys[8 * 512];    // 16 KB
    __shared__ float Y2[8 * 128];    // 4 KB
    const int t = threadIdx.x;
    const float4* yb = (const float4*)(y1s + (size_t)blockIdx.x * 8 * 512);
    const float4* b1v = (const float4*)b1;
    for (int i = t; i < 8 * 128; i += 128) {
        float4 s = yb[i];
        float4 bv = b1v[i & 127];
        float4 y;
        y.x = fmaxf(fmaf(s.x, 256.f, bv.x), 0.f);
        y.y = fmaxf(fmaf(s.y, 256.f, bv.y), 0.f);
        y.z = fmaxf(fmaf(s.z, 256.f, bv.z), 0.f);
        y.w = fmaxf(fmaf(s.w, 256.f, bv.w), 0.f);
        ((float4*)Ys)[i] = y;
    }
    __syncthreads();

    float acc[8];
    float bk = b2[t];
    #pragma unroll
    for (int s = 0; s < 8; ++s) acc[s] = bk;
    const float4* wr = (const float4*)(w2 + (size_t)t * 512);
    for (int jc = 0; jc < 128; ++jc) {
        float4 w4 = wr[jc];
        #pragma unroll
        for (int s = 0; s < 8; ++s) {
            float4 y4 = *(const float4*)(Ys + s * 512 + jc * 4);
            acc[s] += w4.x * y4.x + w4.y * y4.y + w4.z * y4.z + w4.w * y4.w;
        }
    }
    #pragma unroll
    for (int s = 0; s < 8; ++s) Y2[s * 128 + t] = 1.0f / (1.0f + expf(-acc[s]));
    __syncthreads();

    if (t < 8) {
        float sm = b3[0];
        #pragma unroll 4
        for (int k = 0; k < 128; ++k) sm += Y2[t * 128 + k] * w3[k];
        out[n0 + blockIdx.x * 8 + t] = sm;
    }
}

// ---------------------------------------------------------------------------
extern "C" void kernel_launch(void* const* d_in, const int* in_sizes, int n_in,
                              void* d_out, int out_size, void* d_ws, size_t ws_size,
                              hipStream_t stream)
{
    const float* data = (const float*)d_in[0];
    const float* bn_g = (const float*)d_in[1];
    const float* bn_b = (const float*)d_in[2];
    const float* bn_m = (const float*)d_in[3];
    const float* bn_v = (const float*)d_in[4];
    const float* cw   = (const float*)d_in[5];
    const float* cb   = (const float*)d_in[6];
    const float* fc1w = (const float*)d_in[7];
    const float* fc1b = (const float*)d_in[8];
    const float* fc2w = (const float*)d_in[9];
    const float* fc2b = (const float*)d_in[10];
    const float* fc3w = (const float*)d_in[11];
    const float* fc3b = (const float*)d_in[12];
    float* out = (float*)d_out;

    // workspace layout (total ~225.6 MB, known-safe)
    const size_t A16_BYTES = (size_t)CHUNK * K_FC1 * 2;       // 176,947,200
    const size_t W16_BYTES = (size_t)512 * K_FC1 * 2;         //  44,236,800
    const size_t Y1_BYTES  = (size_t)CHUNK * 512 * 4;         //   4,194,304
    if (ws_size < A16_BYTES + W16_BYTES + Y1_BYTES) return;

    char* ws = (char*)d_ws;
    f16*   A16 = (f16*)ws;
    f16*   W16 = (f16*)(ws + A16_BYTES);
    float* y1s = (float*)(ws + A16_BYTES + W16_BYTES);

    // one-time opt-in for 128 KiB dynamic LDS (gfx950 has 160 KiB/CU)
    static int smem_set = 0;
    if (!smem_set) {
        hipFuncSetAttribute(reinterpret_cast<const void*>(gemm_fc1),
                            hipFuncAttributeMaxDynamicSharedMemorySize, 131072);
        smem_set = 1;
    }

    retile_w<<<2 * KT32, 256, 0, stream>>>(fc1w, W16);

    for (int c = 0; c < 2; ++c) {
        int n0 = c * CHUNK;
        hipMemsetAsync(y1s, 0, Y1_BYTES, stream);
        stage_a<<<CHUNK, 256, 0, stream>>>(data, bn_g, bn_b, bn_m, bn_v, cw, cb, A16, n0);
        gemm_fc1<<<256, 512, 131072, stream>>>(A16, W16, y1s);
        head_fc23<<<CHUNK / 8, 128, 0, stream>>>(y1s, fc1b, fc2w, fc2b, fc3w, fc3b, out, n0);
    }
}